// Round 1
// baseline (514.770 us; speedup 1.0000x reference)
//
#include <hip/hip_runtime.h>
#include <float.h>

// x: (B=64, w=512, h=48, M=64) fp32 -> out: (64, 16*6*64) fp32
// Exact uniform bins: row bin = r/32 (16 bins), col bin = c/8 (6 bins).
// out[b, iw*6*64 + ih*64 + m] = max over r in [iw*32, iw*32+32), c in [ih*8, ih*8+8) of x[b,r,c,m]

#define BATCH 64
#define WDIM 512
#define HDIM 48
#define MDIM 64
#define PW 16
#define PH 6
// rows per w-bin = 32, cols per h-bin = 8
// per (b,r): (c,m) plane = 48*64 = 3072 floats = 768 float4, contiguous

__global__ __launch_bounds__(256) void dap_pool_kernel(const float* __restrict__ x,
                                                       float* __restrict__ out) {
    const int blk = blockIdx.x;       // 0..1023
    const int b   = blk >> 4;         // /16
    const int iw  = blk & 15;
    const int t   = threadIdx.x;      // 0..255
    const int m4  = t & 15;           // float4 index within M (m = m4*4 .. m4*4+3)
    const int rr  = t >> 4;           // 0..15 ; covers rows rr and rr+16 of the 32-row bin

    // block's slice: x[b, iw*32 .. iw*32+31, :, :] — contiguous 384 KB
    const float4* base = (const float4*)(x + ((size_t)b * WDIM + (size_t)iw * 32) * (HDIM * MDIM));

    float4 acc[PH];
#pragma unroll
    for (int i = 0; i < PH; ++i)
        acc[i] = make_float4(-FLT_MAX, -FLT_MAX, -FLT_MAX, -FLT_MAX);

#pragma unroll
    for (int rhalf = 0; rhalf < 2; ++rhalf) {
        const int r = rr + rhalf * 16;
        const float4* rowp = base + (size_t)r * (HDIM * MDIM / 4) + m4;
#pragma unroll
        for (int ih = 0; ih < PH; ++ih) {
#pragma unroll
            for (int cc = 0; cc < 8; ++cc) {
                const int c = ih * 8 + cc;
                float4 v = rowp[c * (MDIM / 4)];
                acc[ih].x = fmaxf(acc[ih].x, v.x);
                acc[ih].y = fmaxf(acc[ih].y, v.y);
                acc[ih].z = fmaxf(acc[ih].z, v.z);
                acc[ih].w = fmaxf(acc[ih].w, v.w);
            }
        }
    }

    // reduce across the 16 rr groups via LDS: lds[rr][m4][ih]
    __shared__ float4 lds[16 * 16 * PH];  // 24 KB
#pragma unroll
    for (int ih = 0; ih < PH; ++ih)
        lds[(rr * 16 + m4) * PH + ih] = acc[ih];
    __syncthreads();

    if (t < PH * 16) {          // 96 threads: (ih, m4)
        const int ih = t >> 4;  // 0..5
        const int mm = t & 15;  // 0..15
        float4 r0 = lds[(0 * 16 + mm) * PH + ih];
#pragma unroll
        for (int g = 1; g < 16; ++g) {
            float4 v = lds[(g * 16 + mm) * PH + ih];
            r0.x = fmaxf(r0.x, v.x);
            r0.y = fmaxf(r0.y, v.y);
            r0.z = fmaxf(r0.z, v.z);
            r0.w = fmaxf(r0.w, v.w);
        }
        // out[b, iw*PH*MDIM + ih*MDIM + mm*4 ..+3]  as float4
        float4* o = (float4*)out;
        o[(size_t)b * (PW * PH * MDIM / 4) + iw * (PH * MDIM / 4) + ih * (MDIM / 4) + mm] = r0;
    }
}

extern "C" void kernel_launch(void* const* d_in, const int* in_sizes, int n_in,
                              void* d_out, int out_size, void* d_ws, size_t ws_size,
                              hipStream_t stream) {
    const float* x = (const float*)d_in[0];
    float* out = (float*)d_out;
    dim3 grid(BATCH * PW);   // 1024 blocks: (b, iw)
    dim3 block(256);
    dap_pool_kernel<<<grid, block, 0, stream>>>(x, out);
}